// Round 14
// baseline (259.471 us; speedup 1.0000x reference)
//
#include <hip/hip_runtime.h>
#include <hip/hip_bf16.h>
#include <math.h>

#define EPSBN 1e-3f

typedef __bf16 v8bf __attribute__((ext_vector_type(8)));
typedef float f32x4 __attribute__((ext_vector_type(4)));

__device__ __forceinline__ float hsig(float x) {
    return fminf(fmaxf(0.2f * x + 0.5f, 0.f), 1.f);
}
__device__ __forceinline__ float ftanh(float x) {
    float xa = fminf(fmaxf(x, -10.f), 10.f);
    float e = __expf(2.f * xa);
    return (e - 1.f) / (e + 1.f);
}
__device__ __forceinline__ float bf2f(unsigned short u) {
    union { unsigned int i; float f; } c; c.i = ((unsigned int)u) << 16; return c.f;
}
__device__ __forceinline__ unsigned short f2bu(float x) {
    __bf16 b = (__bf16)x;
    union { __bf16 b; unsigned short u; } c; c.b = b; return c.u;
}

// ---------------------------------------------------------------------------
// Fold BNs + pack MFMA-fragment-ordered bf16 weights.
// P[g][ks][l][j] = W[k][co], co = g*16+(l&15), k = ks*32+(l>>4)*8+j
// Bias folds (blf/b1f/b2f) are wave-parallel: 64 lanes per output channel.
// ---------------------------------------------------------------------------
__global__ void fold_weights(
    const float* __restrict__ bn0g, const float* __restrict__ bn0b,
    const float* __restrict__ bn0m, const float* __restrict__ bn0v,
    const float* __restrict__ w1,   const float* __restrict__ b1,
    const float* __restrict__ bn1g, const float* __restrict__ bn1b,
    const float* __restrict__ bn1m, const float* __restrict__ bn1v,
    const float* __restrict__ w2,   const float* __restrict__ b2,
    const float* __restrict__ bn2g, const float* __restrict__ bn2b,
    const float* __restrict__ bn2m, const float* __restrict__ bn2v,
    const float* __restrict__ wx,   const float* __restrict__ wh,
    const float* __restrict__ blstm,
    const float* __restrict__ wo,   const float* __restrict__ wd1,
    __hip_bfloat16* __restrict__ w1P, float* __restrict__ b1f,
    float* __restrict__ b2f,
    __hip_bfloat16* __restrict__ wxfP, __hip_bfloat16* __restrict__ whP,
    __hip_bfloat16* __restrict__ w2P,
    __hip_bfloat16* __restrict__ woP,  __hip_bfloat16* __restrict__ wd1P,
    float* __restrict__ blf)
{
    int idx = blockIdx.x * 256 + threadIdx.x;
    if (idx < 262144) {                       // whP
        int j = idx & 7, l = (idx >> 3) & 63, ks = (idx >> 9) & 31, g = idx >> 14;
        int co = g * 16 + (l & 15);
        int k  = ks * 32 + (l >> 4) * 8 + j;
        whP[idx] = __float2bfloat16(wh[k * 256 + co]);
    } else if (idx < 393216) {                // wxfP
        int i = idx - 262144;
        int j = i & 7, l = (i >> 3) & 63, ks = (i >> 9) & 15, g = i >> 13;
        int co = g * 16 + (l & 15);
        int k  = ks * 32 + (l >> 4) * 8 + j;
        int ci = k & 31;
        float s = bn2g[ci] * rsqrtf(bn2v[ci] + EPSBN);
        wxfP[i] = __float2bfloat16(wx[k * 256 + co] * s);
    } else if (idx < 394240) {                // w1P
        int i = idx - 393216;
        int j = i & 7, l = (i >> 3) & 63, ks = i >> 9;
        int co = l & 15;
        int k  = ks * 32 + (l >> 4) * 8 + j;
        int ci = k & 3;
        float s = bn0g[ci] * rsqrtf(bn0v[ci] + EPSBN);
        w1P[i] = __float2bfloat16(w1[k * 16 + co] * s);
    } else if (idx < 399360) {                // w2P
        int i = idx - 394240;
        int j = i & 7, l = (i >> 3) & 63;
        int rest = i >> 9;
        int ks = rest % 5, g = rest / 5;
        int co = g * 16 + (l & 15);
        int k  = ks * 32 + (l >> 4) * 8 + j;
        float v = 0.f;
        if (k < 144) {
            int kh = k / 48, r2 = k % 48, kw = r2 / 16, ci = r2 % 16;
            float s = bn1g[ci] * rsqrtf(bn1v[ci] + EPSBN);
            v = w2[((kh * 3 + kw) * 16 + ci) * 32 + co] * s;
        }
        w2P[i] = __float2bfloat16(v);
    } else if (idx < 415744) {                // blf (wave-parallel, K=512)
        int r = idx - 399360;
        int co = r >> 6, lane = r & 63;
        float acc = 0.f;
        #pragma unroll
        for (int i = 0; i < 8; i++) {
            int k = lane + i * 64;
            int ci = k & 31;
            float s = bn2g[ci] * rsqrtf(bn2v[ci] + EPSBN);
            float tt = bn2b[ci] - bn2m[ci] * s;
            acc = fmaf(tt, wx[k * 256 + co], acc);
        }
        #pragma unroll
        for (int off = 32; off; off >>= 1) acc += __shfl_down(acc, off);
        if (lane == 0) blf[co] = acc + blstm[co];
    } else if (idx < 416768) {                // b1f (wave-parallel, K=64)
        int r = idx - 415744;
        int co = r >> 6, lane = r & 63;
        int ci = lane & 3;
        float s = bn0g[ci] * rsqrtf(bn0v[ci] + EPSBN);
        float tt = bn0b[ci] - bn0m[ci] * s;
        float acc = tt * w1[lane * 16 + co];
        #pragma unroll
        for (int off = 32; off; off >>= 1) acc += __shfl_down(acc, off);
        if (lane == 0) b1f[co] = acc + b1[co];
    } else if (idx < 418816) {                // b2f (wave-parallel, K=144)
        int r = idx - 416768;
        int co = r >> 6, lane = r & 63;
        float acc = 0.f;
        #pragma unroll
        for (int i = 0; i < 3; i++) {
            int k = lane + i * 64;
            if (k < 144) {
                int ci = k & 15;
                float s = bn1g[ci] * rsqrtf(bn1v[ci] + EPSBN);
                float tt = bn1b[ci] - bn1m[ci] * s;
                acc = fmaf(tt, w2[k * 32 + co], acc);
            }
        }
        #pragma unroll
        for (int off = 32; off; off >>= 1) acc += __shfl_down(acc, off);
        if (lane == 0) b2f[co] = acc + b2[co];
    } else if (idx < 467968) {                // woP
        int i = idx - 418816;
        int j = i & 7, l = (i >> 3) & 63;
        int rest = i >> 9;
        int ks = rest % 24, g = rest / 24;
        int co = g * 16 + (l & 15);
        int k  = ks * 32 + (l >> 4) * 8 + j;
        woP[i] = __float2bfloat16(wo[k * 64 + co]);
    } else if (idx < 1647616) {               // wd1P
        int i = idx - 467968;
        int j = i & 7, l = (i >> 3) & 63;
        int rest = i >> 9;
        int ks = rest % 288, g = rest / 288;
        int col = g * 16 + (l & 15);
        int k   = ks * 32 + (l >> 4) * 8 + j;
        wd1P[i] = __float2bfloat16(wd1[(size_t)k * 128 + col]);
    }
}

// ---------------------------------------------------------------------------
// conv1 MFMA: img f32 [384,64,64,4] -> act1 bf16 [384,31,31,16]
// ---------------------------------------------------------------------------
__global__ __launch_bounds__(256) void conv1_mfma(
    const float* __restrict__ img,
    const __hip_bfloat16* __restrict__ w1P,
    const float* __restrict__ b1f,
    __hip_bfloat16* __restrict__ act1)
{
    const int tid = threadIdx.x;
    const int l = tid & 63, w = tid >> 6;
    const int cl = l & 15, q = l >> 4;
    const int m0 = (blockIdx.x * 4 + w) * 16;
    const __bf16* wp = reinterpret_cast<const __bf16*>(w1P);

    int pix = m0 + cl;
    int n = pix / 961, p = pix % 961;
    int oy = p / 31, ox = p % 31;

    f32x4 acc = (f32x4){0.f, 0.f, 0.f, 0.f};
    #pragma unroll
    for (int ks = 0; ks < 2; ks++) {
        int kh = ks * 2 + (q >> 1);
        const float* ap = &img[((size_t)(n * 64 + oy * 2 + kh) * 64 + ox * 2) * 4 + (q & 1) * 8];
        float4 v0 = *reinterpret_cast<const float4*>(ap);
        float4 v1 = *reinterpret_cast<const float4*>(ap + 4);
        v8bf a;
        a[0] = (__bf16)v0.x; a[1] = (__bf16)v0.y; a[2] = (__bf16)v0.z; a[3] = (__bf16)v0.w;
        a[4] = (__bf16)v1.x; a[5] = (__bf16)v1.y; a[6] = (__bf16)v1.z; a[7] = (__bf16)v1.w;
        v8bf b = *reinterpret_cast<const v8bf*>(&wp[(size_t)(ks * 64 + l) * 8]);
        acc = __builtin_amdgcn_mfma_f32_16x16x32_bf16(a, b, acc, 0, 0, 0);
    }
    float bias = b1f[cl];
    __bf16* op = reinterpret_cast<__bf16*>(act1);
    #pragma unroll
    for (int reg = 0; reg < 4; reg++)
        op[(size_t)(m0 + q * 4 + reg) * 16 + cl] = (__bf16)fmaxf(acc[reg] + bias, 0.f);
}

// ---------------------------------------------------------------------------
// conv2 MFMA: act1 bf16 [384,31,31,16] -> act2 bf16 [384,15,15,32]
// ---------------------------------------------------------------------------
__global__ __launch_bounds__(128) void conv2_mfma(
    const __hip_bfloat16* __restrict__ act1,
    const __hip_bfloat16* __restrict__ w2P,
    const float* __restrict__ b2f,
    __hip_bfloat16* __restrict__ act2)
{
    const int tid = threadIdx.x;
    const int l = tid & 63, w = tid >> 6;
    const int cl = l & 15, q = l >> 4;
    const int m0 = blockIdx.x * 32;
    const __bf16* a1 = reinterpret_cast<const __bf16*>(act1);
    const __bf16* wp = reinterpret_cast<const __bf16*>(w2P);

    int rbase[2];
    #pragma unroll
    for (int mi = 0; mi < 2; mi++) {
        int row = m0 + mi * 16 + cl;
        int n = row / 225, pos = row % 225;
        int oy = pos / 15, ox = pos % 15;
        rbase[mi] = ((n * 31 + oy * 2) * 31 + ox * 2) * 16;
    }

    f32x4 acc[2];
    acc[0] = (f32x4){0.f, 0.f, 0.f, 0.f};
    acc[1] = (f32x4){0.f, 0.f, 0.f, 0.f};

    #pragma unroll
    for (int ks = 0; ks < 5; ks++) {
        int e = ks * 4 + q;
        int kh = e / 6, r = e % 6, kw = r >> 1, ci0 = (r & 1) * 8;
        v8bf b = *reinterpret_cast<const v8bf*>(&wp[(size_t)((w * 5 + ks) * 64 + l) * 8]);
        #pragma unroll
        for (int mi = 0; mi < 2; mi++) {
            v8bf a = {};
            if (e < 18)
                a = *reinterpret_cast<const v8bf*>(&a1[rbase[mi] + (kh * 31 + kw) * 16 + ci0]);
            acc[mi] = __builtin_amdgcn_mfma_f32_16x16x32_bf16(a, b, acc[mi], 0, 0, 0);
        }
    }

    __bf16* op = reinterpret_cast<__bf16*>(act2);
    int col = w * 16 + cl;
    float bias = b2f[col];
    #pragma unroll
    for (int mi = 0; mi < 2; mi++)
        #pragma unroll
        for (int reg = 0; reg < 4; reg++) {
            int m = m0 + mi * 16 + q * 4 + reg;
            op[(size_t)m * 32 + col] = (__bf16)fmaxf(acc[mi][reg] + bias, 0.f);
        }
}

// ---------------------------------------------------------------------------
// x-conv MFMA: act2 -> zxT bf16 [384][256][144]
// ---------------------------------------------------------------------------
#define XBM 64
__global__ __launch_bounds__(256) void xconv_mfma(
    const __hip_bfloat16* __restrict__ act2,
    const __hip_bfloat16* __restrict__ wxfP,
    const float* __restrict__ blf,
    __hip_bfloat16* __restrict__ zxT)
{
    __shared__ __align__(16) unsigned char smem[XBM * 1024];
    const int tid = threadIdx.x;
    const int l = tid & 63, w = tid >> 6;
    const int cl = l & 15, q = l >> 4;
    const int m0 = blockIdx.x * XBM;
    const __bf16* wp = reinterpret_cast<const __bf16*>(wxfP);

    #pragma unroll 4
    for (int i = 0; i < 16; i++) {
        int r = w * 16 + i;
        int m = m0 + r;
        int n = m / 144, pos = m % 144;
        int oy = pos / 12, ox = pos % 12;
        int iy = oy + q;
        size_t ga = ((size_t)(n * 15 + iy) * 15 + ox) * 32 + cl * 8;
        uint4 v = *reinterpret_cast<const uint4*>(
            reinterpret_cast<const __bf16*>(act2) + ga);
        *reinterpret_cast<uint4*>(&smem[r * 1024 + ((l * 16) ^ ((r & 7) << 4))]) = v;
    }
    __syncthreads();

#define XLDA(mi, ks) (*reinterpret_cast<const v8bf*>( \
    &smem[((mi) * 16 + cl) * 1024 + ((((ks) * 64 + q * 16)) ^ ((cl & 7) << 4))]))
#define XLDB(dst, ks) { _Pragma("unroll") \
    for (int nj = 0; nj < 4; nj++) \
        dst[nj] = *reinterpret_cast<const v8bf*>( \
            &wp[(size_t)(((w * 4 + nj) * 16 + (ks)) * 64 + l) * 8]); }

    f32x4 acc[4][4];
    #pragma unroll
    for (int mi = 0; mi < 4; mi++)
        #pragma unroll
        for (int nj = 0; nj < 4; nj++)
            acc[mi][nj] = (f32x4){0.f, 0.f, 0.f, 0.f};

    v8bf aA[4], aB[4], bA[4], bB[4];
    #pragma unroll
    for (int mi = 0; mi < 4; mi++) aA[mi] = XLDA(mi, 0);
    XLDB(bA, 0);

    #pragma unroll
    for (int ks = 0; ks < 16; ks += 2) {
        #pragma unroll
        for (int mi = 0; mi < 4; mi++) aB[mi] = XLDA(mi, ks + 1);
        XLDB(bB, ks + 1);
        #pragma unroll
        for (int mi = 0; mi < 4; mi++)
            #pragma unroll
            for (int nj = 0; nj < 4; nj++)
                acc[mi][nj] = __builtin_amdgcn_mfma_f32_16x16x32_bf16(
                    aA[mi], bA[nj], acc[mi][nj], 0, 0, 0);
        if (ks + 2 < 16) {
            #pragma unroll
            for (int mi = 0; mi < 4; mi++) aA[mi] = XLDA(mi, ks + 2);
            XLDB(bA, ks + 2);
        }
        #pragma unroll
        for (int mi = 0; mi < 4; mi++)
            #pragma unroll
            for (int nj = 0; nj < 4; nj++)
                acc[mi][nj] = __builtin_amdgcn_mfma_f32_16x16x32_bf16(
                    aB[mi], bB[nj], acc[mi][nj], 0, 0, 0);
    }
#undef XLDA
#undef XLDB

    #pragma unroll
    for (int nj = 0; nj < 4; nj++) {
        int c = w * 64 + nj * 16 + cl;
        float bias = blf[c];
        #pragma unroll
        for (int mi = 0; mi < 4; mi++) {
            int mb = m0 + mi * 16;
            int bt = mb / 144, pos = mb % 144 + q * 4;
            ushort4 v;
            v.x = f2bu(acc[mi][nj][0] + bias);
            v.y = f2bu(acc[mi][nj][1] + bias);
            v.z = f2bu(acc[mi][nj][2] + bias);
            v.w = f2bu(acc[mi][nj][3] + bias);
            *reinterpret_cast<ushort4*>(
                reinterpret_cast<__bf16*>(zxT) + ((size_t)bt * 256 + c) * 144 + pos) = v;
        }
    }
}

// ---------------------------------------------------------------------------
// LSTM step, split-K x4, 16 waves (1024 thr): wave = (kq, wq); each wave
// K in [kq*256, kq*256+256), cols wq*16 within each 64-gate group.
// h_{t-1} staged as compact [5][16][64] bf16 image (10KB).
// Partials summed via zsh[4][16][256] f32 (64KB LDS, unions with image).
// 288 blocks -> 16 waves/CU = 4 waves/SIMD for latency hiding.
// ---------------------------------------------------------------------------
__global__ __launch_bounds__(1024) void lstm_mfma(
    const __hip_bfloat16* __restrict__ zxT,
    const __hip_bfloat16* __restrict__ whP,
    __hip_bfloat16* __restrict__ stacked,
    float* __restrict__ cbuf,
    int t)
{
    __shared__ __align__(16) unsigned char smem[64 * 1024];   // image(10KB)/zsh(64KB)
    const int tid = threadIdx.x;
    const int l = tid & 63, w = tid >> 6;        // 16 waves
    const int cl = l & 15, q = l >> 4;
    const int kq = w >> 2, wq = w & 3;           // K-quarter, col-quad
    const int m0 = blockIdx.x * 16;
    const int b = m0 / 144, pos0 = m0 % 144;
    const int oy_min = pos0 / 12;
    const __bf16* wp = reinterpret_cast<const __bf16*>(whP);
    const __bf16* st = reinterpret_cast<const __bf16*>(stacked);
    const __bf16* zT = reinterpret_cast<const __bf16*>(zxT);

    // kq==0 waves preload z
    ushort4 zr[4];
    if (kq == 0) {
        #pragma unroll
        for (int nj = 0; nj < 4; nj++) {
            int c = nj * 64 + wq * 16 + cl;
            zr[nj] = *reinterpret_cast<const ushort4*>(
                &zT[((size_t)(b * 12 + t) * 256 + c) * 144 + pos0 + q * 4]);
        }
    }

    if (t > 0) {
        // stage image: 600 x 16B chunks, one pass (1024 threads)
        const __bf16* hb = st + (size_t)(t - 1) * 64;
        if (tid < 600) {
            int ird = tid / 120;
            int r = tid % 120;
            int jx = r >> 3, c8 = r & 7;
            int iy = oy_min - 1 + ird;
            int ixa = jx - 1;
            uint4 v = {0u, 0u, 0u, 0u};
            if ((unsigned)iy < 12u && (unsigned)ixa < 12u)
                v = *reinterpret_cast<const uint4*>(
                    &hb[(size_t)(b * 144 + iy * 12 + ixa) * 768 + c8 * 8]);
            *reinterpret_cast<uint4*>(
                &smem[ird * 2048 + jx * 128 + ((c8 ^ (jx & 7)) << 4)]) = v;
        }
        __syncthreads();
    }

    f32x4 acc[4];
    #pragma unroll
    for (int nj = 0; nj < 4; nj++) acc[nj] = (f32x4){0.f, 0.f, 0.f, 0.f};
    if (kq == 0) {
        #pragma unroll
        for (int nj = 0; nj < 4; nj++) {
            acc[nj][0] = bf2f(zr[nj].x);
            acc[nj][1] = bf2f(zr[nj].y);
            acc[nj][2] = bf2f(zr[nj].z);
            acc[nj][3] = bf2f(zr[nj].w);
        }
    }

    if (t > 0) {
        int posL = pos0 + cl;
        int oyL = posL / 12, oxL = posL % 12;
        int rowb = (oyL - oy_min) * 2048;
        int jxb[4], jx7[4];
        #pragma unroll
        for (int kw = 0; kw < 4; kw++) {
            int jx = oxL + kw;
            jxb[kw] = jx * 128;
            jx7[kw] = jx & 7;
        }

// A(ks): k = ks*32+q*8+j -> kh=ks>>3, kw=(ks>>1)&3, slot=(ks&1)*4+q
#define LLDA(ks) (*reinterpret_cast<const v8bf*>( \
    &smem[rowb + ((ks) >> 3) * 2048 + jxb[((ks) >> 1) & 3] + \
          (((((ks) & 1) << 2) + q) ^ jx7[((ks) >> 1) & 3]) * 16]))
#define LLDB(dst, ks) { _Pragma("unroll") \
    for (int nj = 0; nj < 4; nj++) \
        dst[nj] = *reinterpret_cast<const v8bf*>( \
            &wp[(size_t)(((nj * 4 + wq) * 32 + (ks)) * 64 + l) * 8]); }

        const int ks0 = kq * 8;
        v8bf aA, aB, bA[4], bB[4];
        aA = LLDA(ks0);
        LLDB(bA, ks0);
        #pragma unroll
        for (int ks = ks0; ks < ks0 + 8; ks += 2) {
            aB = LLDA(ks + 1);
            LLDB(bB, ks + 1);
            #pragma unroll
            for (int nj = 0; nj < 4; nj++)
                acc[nj] = __builtin_amdgcn_mfma_f32_16x16x32_bf16(aA, bA[nj], acc[nj], 0, 0, 0);
            if (ks + 2 < ks0 + 8) {
                aA = LLDA(ks + 2);
                LLDB(bA, ks + 2);
            }
            #pragma unroll
            for (int nj = 0; nj < 4; nj++)
                acc[nj] = __builtin_amdgcn_mfma_f32_16x16x32_bf16(aB, bB[nj], acc[nj], 0, 0, 0);
        }
#undef LLDA
#undef LLDB
    }

    __syncthreads();                              // all image reads done
    float* zsh = reinterpret_cast<float*>(smem);  // [4][16][256] f32 = 64KB
    #pragma unroll
    for (int nj = 0; nj < 4; nj++) {
        int col = nj * 64 + wq * 16 + cl;
        #pragma unroll
        for (int reg = 0; reg < 4; reg++)
            zsh[kq * 4096 + (q * 4 + reg) * 256 + col] = acc[nj][reg];
    }
    __syncthreads();

    // gate phase: 1024 cells, 1 per thread
    __bf16* so = reinterpret_cast<__bf16*>(stacked);
    {
        int row = tid >> 6, cc = tid & 63;
        int m = m0 + row;
        float zi = 0.f, zf = 0.f, zg = 0.f, zo = 0.f;
        #pragma unroll
        for (int e = 0; e < 4; e++) {
            zi += zsh[e * 4096 + row * 256 + cc];
            zf += zsh[e * 4096 + row * 256 + 64 + cc];
            zg += zsh[e * 4096 + row * 256 + 128 + cc];
            zo += zsh[e * 4096 + row * 256 + 192 + cc];
        }
        float c = (t == 0) ? 0.f : cbuf[(size_t)m * 64 + cc];
        c = hsig(zf) * c + hsig(zi) * ftanh(zg);
        float h = hsig(zo) * ftanh(c);
        cbuf[(size_t)m * 64 + cc] = c;
        so[(size_t)m * 768 + t * 64 + cc] = (__bf16)h;
    }
}

// ---------------------------------------------------------------------------
// compconv MFMA: comp = relu(stacked[4608,768] @ wo + bo) -> bf16 [4608,64]
// ---------------------------------------------------------------------------
__global__ __launch_bounds__(256) void compconv_mfma(
    const __hip_bfloat16* __restrict__ stacked,
    const __hip_bfloat16* __restrict__ woP,
    const float* __restrict__ bo,
    __hip_bfloat16* __restrict__ comp)
{
    const int tid = threadIdx.x;
    const int l = tid & 63, w = tid >> 6;
    const int cl = l & 15, q = l >> 4;
    const int m0 = blockIdx.x * 64 + w * 16;
    const __bf16* st = reinterpret_cast<const __bf16*>(stacked);
    const __bf16* wp = reinterpret_cast<const __bf16*>(woP);

    f32x4 acc[4];
    #pragma unroll
    for (int nj = 0; nj < 4; nj++) acc[nj] = (f32x4){0.f, 0.f, 0.f, 0.f};

    #pragma unroll 4
    for (int ks = 0; ks < 24; ks++) {
        v8bf a = *reinterpret_cast<const v8bf*>(&st[(size_t)(m0 + cl) * 768 + ks * 32 + q * 8]);
        #pragma unroll
        for (int nj = 0; nj < 4; nj++) {
            v8bf b = *reinterpret_cast<const v8bf*>(&wp[(size_t)((nj * 24 + ks) * 64 + l) * 8]);
            acc[nj] = __builtin_amdgcn_mfma_f32_16x16x32_bf16(a, b, acc[nj], 0, 0, 0);
        }
    }
    __bf16* cp = reinterpret_cast<__bf16*>(comp);
    #pragma unroll
    for (int nj = 0; nj < 4; nj++) {
        int c = nj * 16 + cl;
        float bias = bo[c];
        #pragma unroll
        for (int reg = 0; reg < 4; reg++) {
            int m = m0 + q * 4 + reg;
            cp[(size_t)m * 64 + c] = (__bf16)fmaxf(acc[nj][reg] + bias, 0.f);
        }
    }
}

// ---------------------------------------------------------------------------
// dense1 MFMA split-K: 64 blocks = 8 col-groups x 8 K-eighths.
// Each block: partial [32,16] f32 -> hdnPart[e][32][col-group].
// ---------------------------------------------------------------------------
__global__ __launch_bounds__(256) void dense1_mfma(
    const __hip_bfloat16* __restrict__ comp,
    const __hip_bfloat16* __restrict__ wd1P,
    float* __restrict__ hdnPart)            // [8][32][128] f32
{
    __shared__ float red[4][32][16];
    const int tid = threadIdx.x;
    const int l = tid & 63, w = tid >> 6;
    const int cl = l & 15, q = l >> 4;
    const int g = blockIdx.x & 7;            // col-group 0..7
    const int e = blockIdx.x >> 3;           // K-eighth 0..7
    const __bf16* cpp = reinterpret_cast<const __bf16*>(comp);
    const __bf16* wpp = reinterpret_cast<const __bf16*>(wd1P) + (size_t)g * 288 * 512;

    f32x4 acc[2];
    acc[0] = (f32x4){0.f, 0.f, 0.f, 0.f};
    acc[1] = (f32x4){0.f, 0.f, 0.f, 0.f};

    const int ksbase = e * 36 + w * 9;       // 288 = 8 eighths * 4 waves * 9
    for (int ks = ksbase; ks < ksbase + 9; ks++) {
        v8bf b = *reinterpret_cast<const v8bf*>(&wpp[(size_t)ks * 512 + l * 8]);
        #pragma unroll
        for (int mi = 0; mi < 2; mi++) {
            v8bf a = *reinterpret_cast<const v8bf*>(
                &cpp[(size_t)(mi * 16 + cl) * 9216 + ks * 32 + q * 8]);
            acc[mi] = __builtin_amdgcn_mfma_f32_16x16x32_bf16(a, b, acc[mi], 0, 0, 0);
        }
    }
    #pragma unroll
    for (int mi = 0; mi < 2; mi++)
        #pragma unroll
        for (int reg = 0; reg < 4; reg++)
            red[w][mi * 16 + q * 4 + reg][cl] = acc[mi][reg];
    __syncthreads();

    for (int i = tid; i < 512; i += 256) {
        int row = i >> 4, c = i & 15;
        float s = red[0][row][c] + red[1][row][c] + red[2][row][c] + red[3][row][c];
        hdnPart[((size_t)e * 32 + row) * 128 + g * 16 + c] = s;
    }
}

// ---------------------------------------------------------------------------
// dense2 + softmax (sums dense1 partials, applies bias+relu inline)
// ---------------------------------------------------------------------------
__global__ void dense2_k(const float* __restrict__ hdnPart,   // [8][32][128]
                         const float* __restrict__ bd1,
                         const float* __restrict__ wd2,
                         const float* __restrict__ bd2,
                         float* __restrict__ out)
{
    int r = threadIdx.x;
    if (r >= 32) return;
    float l0 = bd2[0], l1 = bd2[1];
    for (int k = 0; k < 128; k++) {
        float s = bd1[k];
        #pragma unroll
        for (int e = 0; e < 8; e++)
            s += hdnPart[((size_t)e * 32 + r) * 128 + k];
        float h = fmaxf(s, 0.f);
        l0 = fmaf(h, wd2[k * 2 + 0], l0);
        l1 = fmaf(h, wd2[k * 2 + 1], l1);
    }
    float mx = fmaxf(l0, l1);
    float e0 = expf(l0 - mx), e1 = expf(l1 - mx);
    float s = e0 + e1;
    out[r * 2 + 0] = e0 / s;
    out[r * 2 + 1] = e1 / s;
}

// ---------------------------------------------------------------------------

extern "C" void kernel_launch(void* const* d_in, const int* in_sizes, int n_in,
                              void* d_out, int out_size, void* d_ws, size_t ws_size,
                              hipStream_t stream)
{
    const float* img   = (const float*)d_in[0];
    const float* bn0g  = (const float*)d_in[1];
    const float* bn0b  = (const float*)d_in[2];
    const float* bn0m  = (const float*)d_in[3];
    const float* bn0v  = (const float*)d_in[4];
    const float* w1    = (const float*)d_in[5];
    const float* b1    = (const float*)d_in[6];
    const float* bn1g  = (const float*)d_in[7];
    const float* bn1b  = (const float*)d_in[8];
    const float* bn1m  = (const float*)d_in[9];
    const float* bn1v  = (const float*)d_in[10];
    const float* w2    = (const float*)d_in[11];
    const float* b2    = (const float*)d_in[12];
    const float* bn2g  = (const float*)d_in[13];
    const float* bn2b  = (const float*)d_in[14];
    const float* bn2m  = (const float*)d_in[15];
    const float* bn2v  = (const float*)d_in[16];
    const float* wx    = (const float*)d_in[17];
    const float* wh    = (const float*)d_in[18];
    const float* blstm = (const float*)d_in[19];
    const float* wo    = (const float*)d_in[20];
    const float* bo    = (const float*)d_in[21];
    const float* wd1   = (const float*)d_in[22];
    const float* bd1   = (const float*)d_in[23];
    const float* wd2   = (const float*)d_in[24];
    const float* bd2   = (const float*)d_in[25];
    float* out = (float*)d_out;

    float* ws = (float*)d_ws;
    size_t o = 0;
    __hip_bfloat16* w1P = (__hip_bfloat16*)(ws + o); o += 512;
    float* b1f = ws + o; o += 16;
    float* b2f = ws + o; o += 32;
    float* blf = ws + o; o += 256;
    __hip_bfloat16* wxfP = (__hip_bfloat16*)(ws + o); o += 65536;
    __hip_bfloat16* whP  = (__hip_bfloat16*)(ws + o); o += 131072;
    __hip_bfloat16* w2P  = (__hip_bfloat16*)(ws + o); o += 2560;
    __hip_bfloat16* woP  = (__hip_bfloat16*)(ws + o); o += 24576;
    __hip_bfloat16* wd1P = (__hip_bfloat16*)(ws + o); o += 589824;
    __hip_bfloat16* act2 = (__hip_bfloat16*)(ws + o); o += 1382400;
    __hip_bfloat16* stacked = (__hip_bfloat16*)(ws + o); o += 1769472;
    float* cbuf = ws + o; o += 294912;
    __hip_bfloat16* comp = (__hip_bfloat16*)(ws + o); o += 147456;
    float* hdnPart = ws + o; o += 32768;      // [8][32][128] f32
    __hip_bfloat16* act1 = (__hip_bfloat16*)(ws + o);
    __hip_bfloat16* zxT  = (__hip_bfloat16*)(ws + o); o += 7077888;

    fold_weights<<<6436, 256, 0, stream>>>(
        bn0g, bn0b, bn0m, bn0v, w1, b1,
        bn1g, bn1b, bn1m, bn1v, w2, b2,
        bn2g, bn2b, bn2m, bn2v, wx, wh, blstm, wo, wd1,
        w1P, b1f, b2f, wxfP, whP, w2P, woP, wd1P, blf);

    conv1_mfma<<<369024 / 64, 256, 0, stream>>>(img, w1P, b1f, act1);
    conv2_mfma<<<86400 / 32, 128, 0, stream>>>(act1, w2P, b2f, act2);
    xconv_mfma<<<55296 / XBM, 256, 0, stream>>>(act2, wxfP, blf, zxT);

    for (int t = 0; t < 12; t++)
        lstm_mfma<<<4608 / 16, 1024, 0, stream>>>(zxT, whP, stacked, cbuf, t);

    compconv_mfma<<<4608 / 64, 256, 0, stream>>>(stacked, woP, bo, comp);
    dense1_mfma<<<64, 256, 0, stream>>>(comp, wd1P, hdnPart);
    dense2_k<<<1, 64, 0, stream>>>(hdnPart, bd1, wd2, bd2, out);
}

// Round 15
// 238.357 us; speedup vs baseline: 1.0886x; 1.0886x over previous
//
#include <hip/hip_runtime.h>
#include <hip/hip_bf16.h>
#include <math.h>

#define EPSBN 1e-3f

typedef __bf16 v8bf __attribute__((ext_vector_type(8)));
typedef float f32x4 __attribute__((ext_vector_type(4)));

__device__ __forceinline__ float hsig(float x) {
    return fminf(fmaxf(0.2f * x + 0.5f, 0.f), 1.f);
}
__device__ __forceinline__ float ftanh(float x) {
    float xa = fminf(fmaxf(x, -10.f), 10.f);
    float e = __expf(2.f * xa);
    return (e - 1.f) / (e + 1.f);
}
__device__ __forceinline__ float bf2f(unsigned short u) {
    union { unsigned int i; float f; } c; c.i = ((unsigned int)u) << 16; return c.f;
}
__device__ __forceinline__ unsigned short f2bu(float x) {
    __bf16 b = (__bf16)x;
    union { __bf16 b; unsigned short u; } c; c.b = b; return c.u;
}

// ---------------------------------------------------------------------------
// Fold BNs + pack MFMA-fragment-ordered bf16 weights.  v3: COALESCED reads —
// each packing range indexed (k, co) with co in the low bits, so consecutive
// lanes read consecutive addresses of the f32 source. P-layout unchanged:
// P[g][ks][l][j] = W[k][co], co=g*16+(l&15), k=ks*32+(l>>4)*8+j.
// ---------------------------------------------------------------------------
__global__ void fold_weights(
    const float* __restrict__ bn0g, const float* __restrict__ bn0b,
    const float* __restrict__ bn0m, const float* __restrict__ bn0v,
    const float* __restrict__ w1,   const float* __restrict__ b1,
    const float* __restrict__ bn1g, const float* __restrict__ bn1b,
    const float* __restrict__ bn1m, const float* __restrict__ bn1v,
    const float* __restrict__ w2,   const float* __restrict__ b2,
    const float* __restrict__ bn2g, const float* __restrict__ bn2b,
    const float* __restrict__ bn2m, const float* __restrict__ bn2v,
    const float* __restrict__ wx,   const float* __restrict__ wh,
    const float* __restrict__ blstm,
    const float* __restrict__ wo,   const float* __restrict__ wd1,
    __hip_bfloat16* __restrict__ w1P, float* __restrict__ b1f,
    float* __restrict__ b2f,
    __hip_bfloat16* __restrict__ wxfP, __hip_bfloat16* __restrict__ whP,
    __hip_bfloat16* __restrict__ w2P,
    __hip_bfloat16* __restrict__ woP,  __hip_bfloat16* __restrict__ wd1P,
    float* __restrict__ blf)
{
    int idx = blockIdx.x * 256 + threadIdx.x;
    if (idx < 262144) {                       // whP: (k,co), co low bits
        int k = idx >> 8, co = idx & 255;
        int g = co >> 4, cl = co & 15;
        int ks = k >> 5, rem = k & 31;
        int l = (rem >> 3) * 16 + cl, j = rem & 7;
        whP[(size_t)((g * 32 + ks) * 64 + l) * 8 + j] = __float2bfloat16(wh[idx]);
    } else if (idx < 393216) {                // wxfP
        int i = idx - 262144;
        int k = i >> 8, co = i & 255;
        int g = co >> 4, cl = co & 15;
        int ks = k >> 5, rem = k & 31;
        int l = (rem >> 3) * 16 + cl, j = rem & 7;
        int ci = k & 31;
        float s = bn2g[ci] * rsqrtf(bn2v[ci] + EPSBN);
        wxfP[(size_t)((g * 16 + ks) * 64 + l) * 8 + j] = __float2bfloat16(wx[i] * s);
    } else if (idx < 394240) {                // w1P
        int i = idx - 393216;
        int k = i >> 4, co = i & 15;
        int ks = k >> 5, rem = k & 31;
        int l = (rem >> 3) * 16 + co, j = rem & 7;
        int ci = k & 3;
        float s = bn0g[ci] * rsqrtf(bn0v[ci] + EPSBN);
        w1P[(size_t)(ks * 64 + l) * 8 + j] = __float2bfloat16(w1[i] * s);
    } else if (idx < 399360) {                // w2P (K padded to 160)
        int i = idx - 394240;
        int k = i >> 5, co = i & 31;
        int g = co >> 4, cl = co & 15;
        int ks = k >> 5, rem = k & 31;
        int l = (rem >> 3) * 16 + cl, j = rem & 7;
        float v = 0.f;
        if (k < 144) {
            int ci = k % 16;
            float s = bn1g[ci] * rsqrtf(bn1v[ci] + EPSBN);
            // k = kh*48 + kw*16 + ci; w2 src index = ((kh*3+kw)*16+ci)*32+co
            int kh = k / 48, r2 = k % 48, kw = r2 / 16;
            v = w2[((kh * 3 + kw) * 16 + ci) * 32 + co] * s;
        }
        w2P[(size_t)((g * 5 + ks) * 64 + l) * 8 + j] = __float2bfloat16(v);
    } else if (idx < 415744) {                // blf (wave-parallel, K=512)
        int r = idx - 399360;
        int co = r >> 6, lane = r & 63;
        float acc = 0.f;
        #pragma unroll
        for (int i = 0; i < 8; i++) {
            int k = lane + i * 64;
            int ci = k & 31;
            float s = bn2g[ci] * rsqrtf(bn2v[ci] + EPSBN);
            float tt = bn2b[ci] - bn2m[ci] * s;
            acc = fmaf(tt, wx[k * 256 + co], acc);
        }
        #pragma unroll
        for (int off = 32; off; off >>= 1) acc += __shfl_down(acc, off);
        if (lane == 0) blf[co] = acc + blstm[co];
    } else if (idx < 416768) {                // b1f (wave-parallel, K=64)
        int r = idx - 415744;
        int co = r >> 6, lane = r & 63;
        int ci = lane & 3;
        float s = bn0g[ci] * rsqrtf(bn0v[ci] + EPSBN);
        float tt = bn0b[ci] - bn0m[ci] * s;
        float acc = tt * w1[lane * 16 + co];
        #pragma unroll
        for (int off = 32; off; off >>= 1) acc += __shfl_down(acc, off);
        if (lane == 0) b1f[co] = acc + b1[co];
    } else if (idx < 418816) {                // b2f (wave-parallel, K=144)
        int r = idx - 416768;
        int co = r >> 6, lane = r & 63;
        float acc = 0.f;
        #pragma unroll
        for (int i = 0; i < 3; i++) {
            int k = lane + i * 64;
            if (k < 144) {
                int ci = k & 15;
                float s = bn1g[ci] * rsqrtf(bn1v[ci] + EPSBN);
                float tt = bn1b[ci] - bn1m[ci] * s;
                acc = fmaf(tt, w2[k * 32 + co], acc);
            }
        }
        #pragma unroll
        for (int off = 32; off; off >>= 1) acc += __shfl_down(acc, off);
        if (lane == 0) b2f[co] = acc + b2[co];
    } else if (idx < 467968) {                // woP
        int i = idx - 418816;
        int k = i >> 6, co = i & 63;
        int g = co >> 4, cl = co & 15;
        int ks = k >> 5, rem = k & 31;
        int l = (rem >> 3) * 16 + cl, j = rem & 7;
        woP[(size_t)((g * 24 + ks) * 64 + l) * 8 + j] = __float2bfloat16(wo[i]);
    } else if (idx < 1647616) {               // wd1P
        int i = idx - 467968;
        int k = i >> 7, col = i & 127;
        int g = col >> 4, cl = col & 15;
        int ks = k >> 5, rem = k & 31;
        int l = (rem >> 3) * 16 + cl, j = rem & 7;
        wd1P[(size_t)((g * 288 + ks) * 64 + l) * 8 + j] = __float2bfloat16(wd1[i]);
    }
}

// ---------------------------------------------------------------------------
// conv1 MFMA: img f32 [384,64,64,4] -> act1 bf16 [384,31,31,16]
// ---------------------------------------------------------------------------
__global__ __launch_bounds__(256) void conv1_mfma(
    const float* __restrict__ img,
    const __hip_bfloat16* __restrict__ w1P,
    const float* __restrict__ b1f,
    __hip_bfloat16* __restrict__ act1)
{
    const int tid = threadIdx.x;
    const int l = tid & 63, w = tid >> 6;
    const int cl = l & 15, q = l >> 4;
    const int m0 = (blockIdx.x * 4 + w) * 16;
    const __bf16* wp = reinterpret_cast<const __bf16*>(w1P);

    int pix = m0 + cl;
    int n = pix / 961, p = pix % 961;
    int oy = p / 31, ox = p % 31;

    f32x4 acc = (f32x4){0.f, 0.f, 0.f, 0.f};
    #pragma unroll
    for (int ks = 0; ks < 2; ks++) {
        int kh = ks * 2 + (q >> 1);
        const float* ap = &img[((size_t)(n * 64 + oy * 2 + kh) * 64 + ox * 2) * 4 + (q & 1) * 8];
        float4 v0 = *reinterpret_cast<const float4*>(ap);
        float4 v1 = *reinterpret_cast<const float4*>(ap + 4);
        v8bf a;
        a[0] = (__bf16)v0.x; a[1] = (__bf16)v0.y; a[2] = (__bf16)v0.z; a[3] = (__bf16)v0.w;
        a[4] = (__bf16)v1.x; a[5] = (__bf16)v1.y; a[6] = (__bf16)v1.z; a[7] = (__bf16)v1.w;
        v8bf b = *reinterpret_cast<const v8bf*>(&wp[(size_t)(ks * 64 + l) * 8]);
        acc = __builtin_amdgcn_mfma_f32_16x16x32_bf16(a, b, acc, 0, 0, 0);
    }
    float bias = b1f[cl];
    __bf16* op = reinterpret_cast<__bf16*>(act1);
    #pragma unroll
    for (int reg = 0; reg < 4; reg++)
        op[(size_t)(m0 + q * 4 + reg) * 16 + cl] = (__bf16)fmaxf(acc[reg] + bias, 0.f);
}

// ---------------------------------------------------------------------------
// conv2 MFMA: act1 bf16 [384,31,31,16] -> act2 bf16 [384,15,15,32]
// ---------------------------------------------------------------------------
__global__ __launch_bounds__(128) void conv2_mfma(
    const __hip_bfloat16* __restrict__ act1,
    const __hip_bfloat16* __restrict__ w2P,
    const float* __restrict__ b2f,
    __hip_bfloat16* __restrict__ act2)
{
    const int tid = threadIdx.x;
    const int l = tid & 63, w = tid >> 6;
    const int cl = l & 15, q = l >> 4;
    const int m0 = blockIdx.x * 32;
    const __bf16* a1 = reinterpret_cast<const __bf16*>(act1);
    const __bf16* wp = reinterpret_cast<const __bf16*>(w2P);

    int rbase[2];
    #pragma unroll
    for (int mi = 0; mi < 2; mi++) {
        int row = m0 + mi * 16 + cl;
        int n = row / 225, pos = row % 225;
        int oy = pos / 15, ox = pos % 15;
        rbase[mi] = ((n * 31 + oy * 2) * 31 + ox * 2) * 16;
    }

    f32x4 acc[2];
    acc[0] = (f32x4){0.f, 0.f, 0.f, 0.f};
    acc[1] = (f32x4){0.f, 0.f, 0.f, 0.f};

    #pragma unroll
    for (int ks = 0; ks < 5; ks++) {
        int e = ks * 4 + q;
        int kh = e / 6, r = e % 6, kw = r >> 1, ci0 = (r & 1) * 8;
        v8bf b = *reinterpret_cast<const v8bf*>(&wp[(size_t)((w * 5 + ks) * 64 + l) * 8]);
        #pragma unroll
        for (int mi = 0; mi < 2; mi++) {
            v8bf a = {};
            if (e < 18)
                a = *reinterpret_cast<const v8bf*>(&a1[rbase[mi] + (kh * 31 + kw) * 16 + ci0]);
            acc[mi] = __builtin_amdgcn_mfma_f32_16x16x32_bf16(a, b, acc[mi], 0, 0, 0);
        }
    }

    __bf16* op = reinterpret_cast<__bf16*>(act2);
    int col = w * 16 + cl;
    float bias = b2f[col];
    #pragma unroll
    for (int mi = 0; mi < 2; mi++)
        #pragma unroll
        for (int reg = 0; reg < 4; reg++) {
            int m = m0 + mi * 16 + q * 4 + reg;
            op[(size_t)m * 32 + col] = (__bf16)fmaxf(acc[mi][reg] + bias, 0.f);
        }
}

// ---------------------------------------------------------------------------
// x-conv MFMA: act2 -> zxT bf16 [384][256][144]
// ---------------------------------------------------------------------------
#define XBM 64
__global__ __launch_bounds__(256) void xconv_mfma(
    const __hip_bfloat16* __restrict__ act2,
    const __hip_bfloat16* __restrict__ wxfP,
    const float* __restrict__ blf,
    __hip_bfloat16* __restrict__ zxT)
{
    __shared__ __align__(16) unsigned char smem[XBM * 1024];
    const int tid = threadIdx.x;
    const int l = tid & 63, w = tid >> 6;
    const int cl = l & 15, q = l >> 4;
    const int m0 = blockIdx.x * XBM;
    const __bf16* wp = reinterpret_cast<const __bf16*>(wxfP);

    #pragma unroll 4
    for (int i = 0; i < 16; i++) {
        int r = w * 16 + i;
        int m = m0 + r;
        int n = m / 144, pos = m % 144;
        int oy = pos / 12, ox = pos % 12;
        int iy = oy + q;
        size_t ga = ((size_t)(n * 15 + iy) * 15 + ox) * 32 + cl * 8;
        uint4 v = *reinterpret_cast<const uint4*>(
            reinterpret_cast<const __bf16*>(act2) + ga);
        *reinterpret_cast<uint4*>(&smem[r * 1024 + ((l * 16) ^ ((r & 7) << 4))]) = v;
    }
    __syncthreads();

#define XLDA(mi, ks) (*reinterpret_cast<const v8bf*>( \
    &smem[((mi) * 16 + cl) * 1024 + ((((ks) * 64 + q * 16)) ^ ((cl & 7) << 4))]))
#define XLDB(dst, ks) { _Pragma("unroll") \
    for (int nj = 0; nj < 4; nj++) \
        dst[nj] = *reinterpret_cast<const v8bf*>( \
            &wp[(size_t)(((w * 4 + nj) * 16 + (ks)) * 64 + l) * 8]); }

    f32x4 acc[4][4];
    #pragma unroll
    for (int mi = 0; mi < 4; mi++)
        #pragma unroll
        for (int nj = 0; nj < 4; nj++)
            acc[mi][nj] = (f32x4){0.f, 0.f, 0.f, 0.f};

    v8bf aA[4], aB[4], bA[4], bB[4];
    #pragma unroll
    for (int mi = 0; mi < 4; mi++) aA[mi] = XLDA(mi, 0);
    XLDB(bA, 0);

    #pragma unroll
    for (int ks = 0; ks < 16; ks += 2) {
        #pragma unroll
        for (int mi = 0; mi < 4; mi++) aB[mi] = XLDA(mi, ks + 1);
        XLDB(bB, ks + 1);
        #pragma unroll
        for (int mi = 0; mi < 4; mi++)
            #pragma unroll
            for (int nj = 0; nj < 4; nj++)
                acc[mi][nj] = __builtin_amdgcn_mfma_f32_16x16x32_bf16(
                    aA[mi], bA[nj], acc[mi][nj], 0, 0, 0);
        if (ks + 2 < 16) {
            #pragma unroll
            for (int mi = 0; mi < 4; mi++) aA[mi] = XLDA(mi, ks + 2);
            XLDB(bA, ks + 2);
        }
        #pragma unroll
        for (int mi = 0; mi < 4; mi++)
            #pragma unroll
            for (int nj = 0; nj < 4; nj++)
                acc[mi][nj] = __builtin_amdgcn_mfma_f32_16x16x32_bf16(
                    aB[mi], bB[nj], acc[mi][nj], 0, 0, 0);
    }
#undef XLDA
#undef XLDB

    #pragma unroll
    for (int nj = 0; nj < 4; nj++) {
        int c = w * 64 + nj * 16 + cl;
        float bias = blf[c];
        #pragma unroll
        for (int mi = 0; mi < 4; mi++) {
            int mb = m0 + mi * 16;
            int bt = mb / 144, pos = mb % 144 + q * 4;
            ushort4 v;
            v.x = f2bu(acc[mi][nj][0] + bias);
            v.y = f2bu(acc[mi][nj][1] + bias);
            v.z = f2bu(acc[mi][nj][2] + bias);
            v.w = f2bu(acc[mi][nj][3] + bias);
            *reinterpret_cast<ushort4*>(
                reinterpret_cast<__bf16*>(zxT) + ((size_t)bt * 256 + c) * 144 + pos) = v;
        }
    }
}

// ---------------------------------------------------------------------------
// LSTM step (round-13 proven): split-K 8-wave + image staging.
// h_{t-1} staged as [5][16][64] bf16 image (10KB, coalesced).
// Waves 0-3: K[0,512), waves 4-7: K[512,1024); partials via zsh in LDS.
// ---------------------------------------------------------------------------
__global__ __launch_bounds__(512) void lstm_mfma(
    const __hip_bfloat16* __restrict__ zxT,
    const __hip_bfloat16* __restrict__ whP,
    __hip_bfloat16* __restrict__ stacked,
    float* __restrict__ cbuf,
    int t)
{
    __shared__ __align__(16) unsigned char smem[16 * 2048];   // image(10KB)/zsh(32KB) union
    const int tid = threadIdx.x;
    const int l = tid & 63, w = tid >> 6;        // 8 waves
    const int cl = l & 15, q = l >> 4;
    const int kh2 = w >> 2, wq = w & 3;          // K-half, col-quad
    const int m0 = blockIdx.x * 16;
    const int b = m0 / 144, pos0 = m0 % 144;
    const int oy_min = pos0 / 12;
    const __bf16* wp = reinterpret_cast<const __bf16*>(whP);
    const __bf16* st = reinterpret_cast<const __bf16*>(stacked);
    const __bf16* zT = reinterpret_cast<const __bf16*>(zxT);

    ushort4 zr[4];
    if (kh2 == 0) {
        #pragma unroll
        for (int nj = 0; nj < 4; nj++) {
            int c = nj * 64 + wq * 16 + cl;
            zr[nj] = *reinterpret_cast<const ushort4*>(
                &zT[((size_t)(b * 12 + t) * 256 + c) * 144 + pos0 + q * 4]);
        }
    }

    if (t > 0) {
        const __bf16* hb = st + (size_t)(t - 1) * 64;
        for (int i = tid; i < 600; i += 512) {
            int ird = i / 120;
            int r = i % 120;
            int jx = r >> 3, c8 = r & 7;
            int iy = oy_min - 1 + ird;
            int ixa = jx - 1;
            uint4 v = {0u, 0u, 0u, 0u};
            if ((unsigned)iy < 12u && (unsigned)ixa < 12u)
                v = *reinterpret_cast<const uint4*>(
                    &hb[(size_t)(b * 144 + iy * 12 + ixa) * 768 + c8 * 8]);
            *reinterpret_cast<uint4*>(
                &smem[ird * 2048 + jx * 128 + ((c8 ^ (jx & 7)) << 4)]) = v;
        }
        __syncthreads();
    }

    f32x4 acc[4];
    #pragma unroll
    for (int nj = 0; nj < 4; nj++) acc[nj] = (f32x4){0.f, 0.f, 0.f, 0.f};
    if (kh2 == 0) {
        #pragma unroll
        for (int nj = 0; nj < 4; nj++) {
            acc[nj][0] = bf2f(zr[nj].x);
            acc[nj][1] = bf2f(zr[nj].y);
            acc[nj][2] = bf2f(zr[nj].z);
            acc[nj][3] = bf2f(zr[nj].w);
        }
    }

    if (t > 0) {
        int posL = pos0 + cl;
        int oyL = posL / 12, oxL = posL % 12;
        int rowb = (oyL - oy_min) * 2048;
        int jxb[4], jx7[4];
        #pragma unroll
        for (int kw = 0; kw < 4; kw++) {
            int jx = oxL + kw;
            jxb[kw] = jx * 128;
            jx7[kw] = jx & 7;
        }

#define LLDA(ks) (*reinterpret_cast<const v8bf*>( \
    &smem[rowb + ((ks) >> 3) * 2048 + jxb[((ks) >> 1) & 3] + \
          (((((ks) & 1) << 2) + q) ^ jx7[((ks) >> 1) & 3]) * 16]))
#define LLDB(dst, ks) { _Pragma("unroll") \
    for (int nj = 0; nj < 4; nj++) \
        dst[nj] = *reinterpret_cast<const v8bf*>( \
            &wp[(size_t)(((nj * 4 + wq) * 32 + (ks)) * 64 + l) * 8]); }

        const int ks0 = kh2 * 16;
        v8bf aA, aB, bA[4], bB[4];
        aA = LLDA(ks0);
        LLDB(bA, ks0);
        #pragma unroll
        for (int ks = ks0; ks < ks0 + 16; ks += 2) {
            aB = LLDA(ks + 1);
            LLDB(bB, ks + 1);
            #pragma unroll
            for (int nj = 0; nj < 4; nj++)
                acc[nj] = __builtin_amdgcn_mfma_f32_16x16x32_bf16(aA, bA[nj], acc[nj], 0, 0, 0);
            if (ks + 2 < ks0 + 16) {
                aA = LLDA(ks + 2);
                LLDB(bA, ks + 2);
            }
            #pragma unroll
            for (int nj = 0; nj < 4; nj++)
                acc[nj] = __builtin_amdgcn_mfma_f32_16x16x32_bf16(aB, bB[nj], acc[nj], 0, 0, 0);
        }
#undef LLDA
#undef LLDB
    }

    __syncthreads();                              // all image reads done
    float* zsh = reinterpret_cast<float*>(smem);  // [2][16][256] f32 = 32KB
    #pragma unroll
    for (int nj = 0; nj < 4; nj++) {
        int col = nj * 64 + wq * 16 + cl;
        #pragma unroll
        for (int reg = 0; reg < 4; reg++)
            zsh[kh2 * 4096 + (q * 4 + reg) * 256 + col] = acc[nj][reg];
    }
    __syncthreads();

    __bf16* so = reinterpret_cast<__bf16*>(stacked);
    for (int i = tid; i < 1024; i += 512) {
        int row = i >> 6, cc = i & 63;
        int m = m0 + row;
        float zi = zsh[row * 256 + cc]        + zsh[4096 + row * 256 + cc];
        float zf = zsh[row * 256 + 64 + cc]   + zsh[4096 + row * 256 + 64 + cc];
        float zg = zsh[row * 256 + 128 + cc]  + zsh[4096 + row * 256 + 128 + cc];
        float zo = zsh[row * 256 + 192 + cc]  + zsh[4096 + row * 256 + 192 + cc];
        float c = (t == 0) ? 0.f : cbuf[(size_t)m * 64 + cc];
        c = hsig(zf) * c + hsig(zi) * ftanh(zg);
        float h = hsig(zo) * ftanh(c);
        cbuf[(size_t)m * 64 + cc] = c;
        so[(size_t)m * 768 + t * 64 + cc] = (__bf16)h;
    }
}

// ---------------------------------------------------------------------------
// compconv MFMA: comp = relu(stacked[4608,768] @ wo + bo) -> bf16 [4608,64]
// ---------------------------------------------------------------------------
__global__ __launch_bounds__(256) void compconv_mfma(
    const __hip_bfloat16* __restrict__ stacked,
    const __hip_bfloat16* __restrict__ woP,
    const float* __restrict__ bo,
    __hip_bfloat16* __restrict__ comp)
{
    const int tid = threadIdx.x;
    const int l = tid & 63, w = tid >> 6;
    const int cl = l & 15, q = l >> 4;
    const int m0 = blockIdx.x * 64 + w * 16;
    const __bf16* st = reinterpret_cast<const __bf16*>(stacked);
    const __bf16* wp = reinterpret_cast<const __bf16*>(woP);

    f32x4 acc[4];
    #pragma unroll
    for (int nj = 0; nj < 4; nj++) acc[nj] = (f32x4){0.f, 0.f, 0.f, 0.f};

    #pragma unroll 4
    for (int ks = 0; ks < 24; ks++) {
        v8bf a = *reinterpret_cast<const v8bf*>(&st[(size_t)(m0 + cl) * 768 + ks * 32 + q * 8]);
        #pragma unroll
        for (int nj = 0; nj < 4; nj++) {
            v8bf b = *reinterpret_cast<const v8bf*>(&wp[(size_t)((nj * 24 + ks) * 64 + l) * 8]);
            acc[nj] = __builtin_amdgcn_mfma_f32_16x16x32_bf16(a, b, acc[nj], 0, 0, 0);
        }
    }
    __bf16* cp = reinterpret_cast<__bf16*>(comp);
    #pragma unroll
    for (int nj = 0; nj < 4; nj++) {
        int c = nj * 16 + cl;
        float bias = bo[c];
        #pragma unroll
        for (int reg = 0; reg < 4; reg++) {
            int m = m0 + q * 4 + reg;
            cp[(size_t)m * 64 + c] = (__bf16)fmaxf(acc[nj][reg] + bias, 0.f);
        }
    }
}

// ---------------------------------------------------------------------------
// dense1 MFMA split-K: 64 blocks = 8 col-groups x 8 K-eighths.
// ---------------------------------------------------------------------------
__global__ __launch_bounds__(256) void dense1_mfma(
    const __hip_bfloat16* __restrict__ comp,
    const __hip_bfloat16* __restrict__ wd1P,
    float* __restrict__ hdnPart)            // [8][32][128] f32
{
    __shared__ float red[4][32][16];
    const int tid = threadIdx.x;
    const int l = tid & 63, w = tid >> 6;
    const int cl = l & 15, q = l >> 4;
    const int g = blockIdx.x & 7;
    const int e = blockIdx.x >> 3;
    const __bf16* cpp = reinterpret_cast<const __bf16*>(comp);
    const __bf16* wpp = reinterpret_cast<const __bf16*>(wd1P) + (size_t)g * 288 * 512;

    f32x4 acc[2];
    acc[0] = (f32x4){0.f, 0.f, 0.f, 0.f};
    acc[1] = (f32x4){0.f, 0.f, 0.f, 0.f};

    const int ksbase = e * 36 + w * 9;
    for (int ks = ksbase; ks < ksbase + 9; ks++) {
        v8bf b = *reinterpret_cast<const v8bf*>(&wpp[(size_t)ks * 512 + l * 8]);
        #pragma unroll
        for (int mi = 0; mi < 2; mi++) {
            v8bf a = *reinterpret_cast<const v8bf*>(
                &cpp[(size_t)(mi * 16 + cl) * 9216 + ks * 32 + q * 8]);
            acc[mi] = __builtin_amdgcn_mfma_f32_16x16x32_bf16(a, b, acc[mi], 0, 0, 0);
        }
    }
    #pragma unroll
    for (int mi = 0; mi < 2; mi++)
        #pragma unroll
        for (int reg = 0; reg < 4; reg++)
            red[w][mi * 16 + q * 4 + reg][cl] = acc[mi][reg];
    __syncthreads();

    for (int i = tid; i < 512; i += 256) {
        int row = i >> 4, c = i & 15;
        float s = red[0][row][c] + red[1][row][c] + red[2][row][c] + red[3][row][c];
        hdnPart[((size_t)e * 32 + row) * 128 + g * 16 + c] = s;
    }
}

// ---------------------------------------------------------------------------
// dense2 + softmax (sums dense1 partials, applies bias+relu inline)
// ---------------------------------------------------------------------------
__global__ void dense2_k(const float* __restrict__ hdnPart,   // [8][32][128]
                         const float* __restrict__ bd1,
                         const float* __restrict__ wd2,
                         const float* __restrict__ bd2,
                         float* __restrict__ out)
{
    int r = threadIdx.x;
    if (r >= 32) return;
    float l0 = bd2[0], l1 = bd2[1];
    for (int k = 0; k < 128; k++) {
        float s = bd1[k];
        #pragma unroll
        for (int e = 0; e < 8; e++)
            s += hdnPart[((size_t)e * 32 + r) * 128 + k];
        float h = fmaxf(s, 0.f);
        l0 = fmaf(h, wd2[k * 2 + 0], l0);
        l1 = fmaf(h, wd2[k * 2 + 1], l1);
    }
    float mx = fmaxf(l0, l1);
    float e0 = expf(l0 - mx), e1 = expf(l1 - mx);
    float s = e0 + e1;
    out[r * 2 + 0] = e0 / s;
    out[r * 2 + 1] = e1 / s;
}

// ---------------------------------------------------------------------------

extern "C" void kernel_launch(void* const* d_in, const int* in_sizes, int n_in,
                              void* d_out, int out_size, void* d_ws, size_t ws_size,
                              hipStream_t stream)
{
    const float* img   = (const float*)d_in[0];
    const float* bn0g  = (const float*)d_in[1];
    const float* bn0b  = (const float*)d_in[2];
    const float* bn0m  = (const float*)d_in[3];
    const float* bn0v  = (const float*)d_in[4];
    const float* w1    = (const float*)d_in[5];
    const float* b1    = (const float*)d_in[6];
    const float* bn1g  = (const float*)d_in[7];
    const float* bn1b  = (const float*)d_in[8];
    const float* bn1m  = (const float*)d_in[9];
    const float* bn1v  = (const float*)d_in[10];
    const float* w2    = (const float*)d_in[11];
    const float* b2    = (const float*)d_in[12];
    const float* bn2g  = (const float*)d_in[13];
    const float* bn2b  = (const float*)d_in[14];
    const float* bn2m  = (const float*)d_in[15];
    const float* bn2v  = (const float*)d_in[16];
    const float* wx    = (const float*)d_in[17];
    const float* wh    = (const float*)d_in[18];
    const float* blstm = (const float*)d_in[19];
    const float* wo    = (const float*)d_in[20];
    const float* bo    = (const float*)d_in[21];
    const float* wd1   = (const float*)d_in[22];
    const float* bd1   = (const float*)d_in[23];
    const float* wd2   = (const float*)d_in[24];
    const float* bd2   = (const float*)d_in[25];
    float* out = (float*)d_out;

    float* ws = (float*)d_ws;
    size_t o = 0;
    __hip_bfloat16* w1P = (__hip_bfloat16*)(ws + o); o += 512;
    float* b1f = ws + o; o += 16;
    float* b2f = ws + o; o += 32;
    float* blf = ws + o; o += 256;
    __hip_bfloat16* wxfP = (__hip_bfloat16*)(ws + o); o += 65536;
    __hip_bfloat16* whP  = (__hip_bfloat16*)(ws + o); o += 131072;
    __hip_bfloat16* w2P  = (__hip_bfloat16*)(ws + o); o += 2560;
    __hip_bfloat16* woP  = (__hip_bfloat16*)(ws + o); o += 24576;
    __hip_bfloat16* wd1P = (__hip_bfloat16*)(ws + o); o += 589824;
    __hip_bfloat16* act2 = (__hip_bfloat16*)(ws + o); o += 1382400;
    __hip_bfloat16* stacked = (__hip_bfloat16*)(ws + o); o += 1769472;
    float* cbuf = ws + o; o += 294912;
    __hip_bfloat16* comp = (__hip_bfloat16*)(ws + o); o += 147456;
    float* hdnPart = ws + o; o += 32768;      // [8][32][128] f32
    __hip_bfloat16* act1 = (__hip_bfloat16*)(ws + o);
    __hip_bfloat16* zxT  = (__hip_bfloat16*)(ws + o); o += 7077888;

    fold_weights<<<6436, 256, 0, stream>>>(
        bn0g, bn0b, bn0m, bn0v, w1, b1,
        bn1g, bn1b, bn1m, bn1v, w2, b2,
        bn2g, bn2b, bn2m, bn2v, wx, wh, blstm, wo, wd1,
        w1P, b1f, b2f, wxfP, whP, w2P, woP, wd1P, blf);

    conv1_mfma<<<369024 / 64, 256, 0, stream>>>(img, w1P, b1f, act1);
    conv2_mfma<<<86400 / 32, 128, 0, stream>>>(act1, w2P, b2f, act2);
    xconv_mfma<<<55296 / XBM, 256, 0, stream>>>(act2, wxfP, blf, zxT);

    for (int t = 0; t < 12; t++)
        lstm_mfma<<<4608 / 16, 512, 0, stream>>>(zxT, whP, stacked, cbuf, t);

    compconv_mfma<<<4608 / 64, 256, 0, stream>>>(stacked, woP, bo, comp);
    dense1_mfma<<<64, 256, 0, stream>>>(comp, wd1P, hdnPart);
    dense2_k<<<1, 64, 0, stream>>>(hdnPart, bd1, wd2, bd2, out);
}